// Round 2
// baseline (54.499 us; speedup 1.0000x reference)
//
#include <hip/hip_runtime.h>
#include <math.h>

// CGP elementwise DAG: 4,194,304 rows x 8 f32 in -> 8 f32 out.
// R1: 44.8 us, FETCH_SIZE showed ~50% of reads already L3-hit (input 128 MiB
// fits in 256 MiB Infinity Cache, but output write-allocation evicts half).
// R2: non-temporal stores -> output streams to HBM without polluting L3,
// input stays fully L3-resident; floor becomes write-stream ~19-21 us.

using f4 = __attribute__((ext_vector_type(4))) float;

__global__ __launch_bounds__(256) void CGPLayer_60773787239141_kernel(
    const float* __restrict__ x,
    const float* __restrict__ ephs,
    float* __restrict__ out,
    int batch)
{
    const float c0 = ephs[0];
    const float c1 = ephs[1];
    const float c2 = ephs[2];
    const float c3 = ephs[3];

    int tid    = blockIdx.x * blockDim.x + threadIdx.x;
    int stride = gridDim.x * blockDim.x;

    for (int row = tid; row < batch; row += stride) {
        const f4* __restrict__ xp =
            reinterpret_cast<const f4*>(x) + (size_t)row * 2;
        f4 a = xp[0];   // x0..x3
        f4 b = xp[1];   // x4..x7

        float n0  = a.x + a.y;          // add
        float n1  = a.z * a.w;          // mul
        float n2  = sinf(b.x);          // sin
        float n3  = tanhf(b.y + c0);    // add -> tanh
        float n4  = n0 * n1;            // mul
        float n5  = n2 + n3;            // add
        float n6  = n4 - n5;            // sub
        float n7  = cosf(n6);           // cos
        float n8  = n0 * c1;            // mul const
        float n9  = n7 + n8;            // add
        float n10 = tanhf(n9);          // tanh
        float n11 = b.z * b.w;          // mul
        float n12 = n11 + c2;           // add const
        float n13 = sinf(n12);          // sin
        float n14 = n10 * n13;          // mul
        float n15 = n14 + c3;           // add const

        f4 o0 = { n15, n10, n13, n9  };
        f4 o1 = { n4,  n5,  n7,  n12 };

        f4* __restrict__ op = reinterpret_cast<f4*>(out) + (size_t)row * 2;
        __builtin_nontemporal_store(o0, op);       // stream, no L3 alloc
        __builtin_nontemporal_store(o1, op + 1);
    }
}

extern "C" void kernel_launch(void* const* d_in, const int* in_sizes, int n_in,
                              void* d_out, int out_size, void* d_ws, size_t ws_size,
                              hipStream_t stream) {
    const float* x    = (const float*)d_in[0];
    const float* ephs = (const float*)d_in[1];
    float* out        = (float*)d_out;
    int batch = in_sizes[0] / 8;   // 4,194,304

    const int block = 256;
    const int grid  = 2048;        // grid-stride, ~8 rows/thread
    hipLaunchKernelGGL(CGPLayer_60773787239141_kernel,
                       dim3(grid), dim3(block), 0, stream,
                       x, ephs, out, batch);
}

// Round 3
// 44.562 us; speedup vs baseline: 1.2230x; 1.2230x over previous
//
#include <hip/hip_runtime.h>
#include <math.h>

// CGP elementwise DAG: 4,194,304 rows x 8 f32 in -> 8 f32 out.
// R1: plain stores, 44.8 us (~95% of 6.3 TB/s mixed-stream ceiling).
// R2: nt stores REGRESSED (54.5 us): WRITE_SIZE +15% (bypasses L2 write
//     combining), FETCH unchanged (TCC-edge counter, L3 hits still counted).
// R3: revert nt; grid 2048->4096, unroll x2 (4 loads in flight/thread)
//     to push occupancy/MLP toward the write-stream ceiling (~7 TB/s).

using f4 = __attribute__((ext_vector_type(4))) float;

__device__ __forceinline__ void cgp_row(const f4& a, const f4& b,
                                        float c0, float c1, float c2, float c3,
                                        f4& o0, f4& o1)
{
    float n0  = a.x + a.y;          // add
    float n1  = a.z * a.w;          // mul
    float n2  = sinf(b.x);          // sin
    float n3  = tanhf(b.y + c0);    // add -> tanh
    float n4  = n0 * n1;            // mul
    float n5  = n2 + n3;            // add
    float n6  = n4 - n5;            // sub
    float n7  = cosf(n6);           // cos
    float n8  = n0 * c1;            // mul const
    float n9  = n7 + n8;            // add
    float n10 = tanhf(n9);          // tanh
    float n11 = b.z * b.w;          // mul
    float n12 = n11 + c2;           // add const
    float n13 = sinf(n12);          // sin
    float n14 = n10 * n13;          // mul
    float n15 = n14 + c3;           // add const

    o0 = f4{ n15, n10, n13, n9  };
    o1 = f4{ n4,  n5,  n7,  n12 };
}

__global__ __launch_bounds__(256) void CGPLayer_60773787239141_kernel(
    const float* __restrict__ x,
    const float* __restrict__ ephs,
    float* __restrict__ out,
    int batch)
{
    const float c0 = ephs[0];
    const float c1 = ephs[1];
    const float c2 = ephs[2];
    const float c3 = ephs[3];

    int tid    = blockIdx.x * blockDim.x + threadIdx.x;
    int stride = gridDim.x * blockDim.x;

    // Unroll x2: two rows per iteration, all 4 loads issued before compute.
    int row = tid;
    for (; row + stride < batch; row += 2 * stride) {
        int r0 = row;
        int r1 = row + stride;
        const f4* __restrict__ p0 = reinterpret_cast<const f4*>(x) + (size_t)r0 * 2;
        const f4* __restrict__ p1 = reinterpret_cast<const f4*>(x) + (size_t)r1 * 2;
        f4 a0 = p0[0], b0 = p0[1];
        f4 a1 = p1[0], b1 = p1[1];

        f4 o00, o01, o10, o11;
        cgp_row(a0, b0, c0, c1, c2, c3, o00, o01);
        cgp_row(a1, b1, c0, c1, c2, c3, o10, o11);

        f4* __restrict__ q0 = reinterpret_cast<f4*>(out) + (size_t)r0 * 2;
        f4* __restrict__ q1 = reinterpret_cast<f4*>(out) + (size_t)r1 * 2;
        q0[0] = o00; q0[1] = o01;
        q1[0] = o10; q1[1] = o11;
    }
    // tail
    for (; row < batch; row += stride) {
        const f4* __restrict__ p = reinterpret_cast<const f4*>(x) + (size_t)row * 2;
        f4 a = p[0], b = p[1];
        f4 o0, o1;
        cgp_row(a, b, c0, c1, c2, c3, o0, o1);
        f4* __restrict__ q = reinterpret_cast<f4*>(out) + (size_t)row * 2;
        q[0] = o0; q[1] = o1;
    }
}

extern "C" void kernel_launch(void* const* d_in, const int* in_sizes, int n_in,
                              void* d_out, int out_size, void* d_ws, size_t ws_size,
                              hipStream_t stream) {
    const float* x    = (const float*)d_in[0];
    const float* ephs = (const float*)d_in[1];
    float* out        = (float*)d_out;
    int batch = in_sizes[0] / 8;   // 4,194,304

    const int block = 256;
    const int grid  = 4096;        // 4 rows/thread, unroll x2 -> 2 iterations
    hipLaunchKernelGGL(CGPLayer_60773787239141_kernel,
                       dim3(grid), dim3(block), 0, stream,
                       x, ephs, out, batch);
}